// Round 4
// baseline (371.945 us; speedup 1.0000x reference)
//
#include <hip/hip_runtime.h>
#include <math.h>

// LeCun LCN, fused single kernel, radius-5 truncated Gaussian.
//
// mean     = gauss11x11 * x          (separable, zero-pad SAME)
// centered = x - mean
// var      = gauss11x11 * centered^2 (zero-pad SAME)
// out      = centered / (sqrt(var) + 1e-4) * mask
//
// Tile 32x32 (96 flat cols), 256 threads, LDS 49.6 KB -> 3 blocks/CU:
//  P1: hblur(x)  -> s1[52][132]   rows h0-10..h0+41, flat cols fc0..fc0+125
//      (row tasks, float4 global window loads, b128 LDS writes)
//  P2: vblur(s1)=mean; centered=x-mean -> b2[42][132]  rows h0-5..h0+36
//      (column-rolling: thread-per-col, 11-reg window, b32 lane-consecutive)
//  P3: hblur(b2^2) -> hc[42][100] (overlays s1)  (row tasks, b128)
//  P4: vblur(hc)=var; epilogue    (column-rolling, b32, coalesced stores)
//
// Strides 132 (=4 mod 32) / 100 (=4 mod 32) rotate bank quads per row so the
// b128 phases hit all 8 quads; column phases are lane-consecutive b32 (free).

#define TW 32
#define TH 32
#define S1W 132          // s1/b2 row stride (126 cols used)
#define S1R 52           // TH + 20
#define B2R 42           // TH + 10
#define HCW 100          // hc row stride (96 cols used)

__global__ __launch_bounds__(256, 3)
void lecun_lcn_kernel(const float* __restrict__ x,
                      const float* __restrict__ mask,
                      float* __restrict__ out)
{
    __shared__ float s1[S1R * S1W];   // 27,456 B (hc overlays: 42*100*4=16.8K)
    __shared__ float b2[B2R * S1W];   // 22,176 B

    const int tid = threadIdx.x;
    const int w0  = blockIdx.x * TW;
    const int h0  = blockIdx.y * TH;
    const int bi  = blockIdx.z;
    const int fc0 = 3 * w0 - 15;      // flat col of s1/b2 col index 0

    const float K[6] = {
        3.9894227826685783e-01f,
        2.4197072322439816e-01f,
        5.3990966224238430e-02f,
        4.4318483882270000e-03f,
        1.3383022504889000e-04f,
        1.4867195067806000e-06f
    };

    const float* xb = x + (size_t)bi * 512 * 1536;

    // ---------------- Phase 1: hblur(x) -> s1 (row tasks) -------------------
    for (int t = tid; t < S1R * 16; t += 256) {
        const int r   = t >> 4;
        const int run = t & 15;
        const int h   = h0 - 10 + r;
        float* dst = &s1[r * S1W + run * 8];
        if ((unsigned)h >= 512u) {
            float4 z = make_float4(0.f, 0.f, 0.f, 0.f);
            ((float4*)dst)[0] = z; ((float4*)dst)[1] = z;
            continue;
        }
        const float* xrow = xb + (size_t)h * 1536;
        const int gc0 = fc0 + run * 8;     // first output flat col
        const int a   = gc0 - 17;          // window start; a % 4 == 0
        float w[40];                       // covers [gc0-17, gc0+22]
        if (a >= 0 && a <= 1536 - 40) {
            const float4* p = (const float4*)(xrow + a);
            #pragma unroll
            for (int q = 0; q < 10; ++q) {
                float4 v = p[q];
                w[4*q+0] = v.x; w[4*q+1] = v.y; w[4*q+2] = v.z; w[4*q+3] = v.w;
            }
        } else {
            #pragma unroll
            for (int i = 0; i < 40; ++i) {
                int j = a + i;
                w[i] = ((unsigned)j < 1536u) ? xrow[j] : 0.0f;
            }
        }
        float v1[8];
        #pragma unroll
        for (int i = 0; i < 8; ++i) {
            const int ci = 17 + i;
            float acc = K[0] * w[ci];
            #pragma unroll
            for (int d = 1; d <= 5; ++d)
                acc = fmaf(K[d], w[ci - 3*d] + w[ci + 3*d], acc);
            v1[i] = acc;
        }
        ((float4*)dst)[0] = make_float4(v1[0], v1[1], v1[2], v1[3]);
        ((float4*)dst)[1] = make_float4(v1[4], v1[5], v1[6], v1[7]);
    }
    __syncthreads();

    // ------- Phase 2: column-rolling vblur(s1)=mean; centered -> b2 ---------
    {
        const int c  = tid & 127;          // s1/b2 column
        const int rg = tid >> 7;           // 0: rows 0..20, 1: rows 21..41
        if (c < 126) {
            const int base = rg * 21;
            const int gc   = fc0 + c;
            const bool cin = (unsigned)gc < 1536u;
            float w[11];
            #pragma unroll
            for (int i = 0; i < 10; ++i) w[i] = s1[(base + i) * S1W + c];
            #pragma unroll
            for (int rr = 0; rr < 21; ++rr) {
                w[(rr + 10) % 11] = s1[(base + rr + 10) * S1W + c];
                float mean = K[0] * w[(rr + 5) % 11];
                #pragma unroll
                for (int d = 1; d <= 5; ++d)
                    mean = fmaf(K[d], w[(rr + 5 - d) % 11] + w[(rr + 5 + d) % 11], mean);
                const int r = base + rr;           // b2 row
                const int h = h0 - 5 + r;          // image row (wave-uniform)
                float ce = 0.0f;
                if ((unsigned)h < 512u && cin) {
                    ce = xb[(size_t)h * 1536 + gc] - mean;
                }
                b2[r * S1W + c] = ce;
            }
        }
    }
    __syncthreads();

    // ---------------- Phase 3: hblur(b2^2) -> hc (overlays s1) --------------
    float* hc = s1;                        // 42 x 100
    for (int t = tid; t < B2R * 12; t += 256) {
        const int r   = t / 12;
        const int run = t - r * 12;
        const int tc0 = run * 8;           // tile flat col of first output
        float w[40];                       // b2 cols [tc0, tc0+40)
        const float4* p = (const float4*)&b2[r * S1W + tc0];
        #pragma unroll
        for (int q = 0; q < 10; ++q) {
            float4 v = p[q];
            w[4*q+0] = v.x * v.x; w[4*q+1] = v.y * v.y;
            w[4*q+2] = v.z * v.z; w[4*q+3] = v.w * v.w;
        }
        float v1[8];
        #pragma unroll
        for (int i = 0; i < 8; ++i) {
            const int ci = 15 + i;         // center: b2 col tc0+i+15
            float acc = K[0] * w[ci];
            #pragma unroll
            for (int d = 1; d <= 5; ++d)
                acc = fmaf(K[d], w[ci - 3*d] + w[ci + 3*d], acc);
            v1[i] = acc;
        }
        float4* dst = (float4*)&hc[r * HCW + tc0];
        dst[0] = make_float4(v1[0], v1[1], v1[2], v1[3]);
        dst[1] = make_float4(v1[4], v1[5], v1[6], v1[7]);
    }
    __syncthreads();

    // ------- Phase 4: column-rolling vblur(hc)=var; epilogue ----------------
    if (tid < 192) {
        const int c  = tid % 96;           // tile flat col
        const int rg = tid / 96;           // 0: rows 0..15, 1: rows 16..31
        const int base = rg * 16;
        const int cw = c / 3;
        float w[11];
        #pragma unroll
        for (int i = 0; i < 10; ++i) w[i] = hc[(base + i) * HCW + c];
        #pragma unroll
        for (int rr = 0; rr < 16; ++rr) {
            w[(rr + 10) % 11] = hc[(base + rr + 10) * HCW + c];
            float var = K[0] * w[(rr + 5) % 11];
            #pragma unroll
            for (int d = 1; d <= 5; ++d)
                var = fmaf(K[d], w[(rr + 5 - d) % 11] + w[(rr + 5 + d) % 11], var);
            const int r = base + rr;
            const int h = h0 + r;
            const size_t rowoff = (size_t)(bi * 512 + h);
            const float ce = b2[(r + 5) * S1W + (c + 15)];
            const float mv = mask[rowoff * 512 + w0 + cw];
            out[rowoff * 1536 + 3 * w0 + c] =
                ce * __builtin_amdgcn_rcpf(sqrtf(var) + 1e-4f) * mv;
        }
    }
}

extern "C" void kernel_launch(void* const* d_in, const int* in_sizes, int n_in,
                              void* d_out, int out_size, void* d_ws, size_t ws_size,
                              hipStream_t stream) {
    const float* x0   = (const float*)d_in[0];
    const float* mask = (const float*)d_in[1];
    float* out = (float*)d_out;

    dim3 grid(512 / TW, 512 / TH, 32);   // (16, 16, 32) = 8192 blocks
    dim3 block(256);
    lecun_lcn_kernel<<<grid, block, 0, stream>>>(x0, mask, out);
}